// Round 2
// baseline (323.844 us; speedup 1.0000x reference)
//
#include <hip/hip_runtime.h>
#include <hip/hip_bf16.h>

// Problem constants
#define BB   4
#define SS   2048
#define DIN  1024
#define DOUT 1024
#define NH   16
#define HDIM 64

typedef __hip_bfloat16 bf16;
typedef __attribute__((ext_vector_type(8))) short short8;   // bf16 MFMA A/B frag (4 VGPR)
typedef __attribute__((ext_vector_type(4))) float floatx4;  // MFMA C/D frag

#define AS1(p) ((const __attribute__((address_space(1))) void*)(p))
#define AS3(p) ((__attribute__((address_space(3))) void*)(p))

// ---------------------------------------------------------------- cast fp32 -> bf16
__global__ void cast_f32_bf16_kernel(const float* __restrict__ src, bf16* __restrict__ dst) {
    size_t i = ((size_t)blockIdx.x * 256 + threadIdx.x) * 8;
    float4 a = *(const float4*)(src + i);
    float4 b = *(const float4*)(src + i + 4);
    bf16 o[8] __attribute__((aligned(16)));
    o[0] = __float2bfloat16(a.x); o[1] = __float2bfloat16(a.y);
    o[2] = __float2bfloat16(a.z); o[3] = __float2bfloat16(a.w);
    o[4] = __float2bfloat16(b.x); o[5] = __float2bfloat16(b.y);
    o[6] = __float2bfloat16(b.z); o[7] = __float2bfloat16(b.w);
    *(short8*)(dst + i) = *(short8*)o;
}

// ------------------------------------------- build Wqkv^T (bf16, rows = output col n, cols = k)
__global__ void prep_wqkv_kernel(const float* __restrict__ Wq, const float* __restrict__ Wk,
                                 const float* __restrict__ Wv, bf16* __restrict__ wt) {
    __shared__ float tile[64][65];
    const int kt = blockIdx.x;          // 16 k-tiles
    const int nt = blockIdx.y;          // 48 n-tiles
    const int k0 = kt * 64, n0 = nt * 64;
    const float* W = (n0 < 1024) ? Wq : (n0 < 2048 ? Wk : Wv);
    const int col0 = n0 & 1023;
    const int tid = threadIdx.x;
    {
        const int kl = tid >> 2, nc = (tid & 3) * 16;
        const float* src = W + (size_t)(k0 + kl) * 1024 + col0 + nc;
        #pragma unroll
        for (int i = 0; i < 16; i += 4) {
            float4 v = *(const float4*)(src + i);
            tile[kl][nc + i + 0] = v.x; tile[kl][nc + i + 1] = v.y;
            tile[kl][nc + i + 2] = v.z; tile[kl][nc + i + 3] = v.w;
        }
    }
    __syncthreads();
    {
        const int nl = tid >> 2, kc = (tid & 3) * 16;
        bf16 o[16] __attribute__((aligned(16)));
        #pragma unroll
        for (int i = 0; i < 16; ++i) o[i] = __float2bfloat16(tile[kc + i][nl]);
        bf16* dst = wt + (size_t)(n0 + nl) * 1024 + k0 + kc;
        *(short8*)dst       = *(short8*)&o[0];
        *(short8*)(dst + 8) = *(short8*)&o[8];
    }
}

// ---------------------------------------------------------------- GEMM: C = A @ Bt^T (m97 structure)
// kept for the small out-projection (EPI=1) this round
template<int EPI>
__global__ __launch_bounds__(256) void gemm_bt_kernel(
    const bf16* __restrict__ A, const bf16* __restrict__ Bt,
    void* __restrict__ C, const float* __restrict__ bias, int K, int ldc) {
    __shared__ __align__(16) bf16 As[128][32];
    __shared__ __align__(16) bf16 Bs[128][32];
    const int tid  = threadIdx.x;
    const int wave = tid >> 6, lane = tid & 63;
    const int lm   = lane & 15, quad = lane >> 4;
    const int wm   = (wave >> 1) * 64, wn = (wave & 1) * 64;
    const size_t rowA0 = (size_t)blockIdx.x * 128;
    const size_t rowB0 = (size_t)blockIdx.y * 128;
    const int srow = wave * 16 + (lane >> 2);
    const int skc  = (lane & 3) * 8;

    floatx4 acc[4][4] = {};

    for (int k0 = 0; k0 < K; k0 += 32) {
        __syncthreads();
        #pragma unroll
        for (int r = 0; r < 2; ++r) {
            const bf16* gA = A  + (rowA0 + r * 64 + srow) * (size_t)K + k0 + skc;
            __builtin_amdgcn_global_load_lds(AS1(gA), AS3(&As[r * 64 + wave * 16][0]), 16, 0, 0);
            const bf16* gB = Bt + (rowB0 + r * 64 + srow) * (size_t)K + k0 + skc;
            __builtin_amdgcn_global_load_lds(AS1(gB), AS3(&Bs[r * 64 + wave * 16][0]), 16, 0, 0);
        }
        __syncthreads();
        short8 a[4], b[4];
        #pragma unroll
        for (int i = 0; i < 4; ++i) a[i] = *(const short8*)&As[wm + i * 16 + lm][quad * 8];
        #pragma unroll
        for (int j = 0; j < 4; ++j) b[j] = *(const short8*)&Bs[wn + j * 16 + lm][quad * 8];
        #pragma unroll
        for (int i = 0; i < 4; ++i)
            #pragma unroll
            for (int j = 0; j < 4; ++j)
                acc[i][j] = __builtin_amdgcn_mfma_f32_16x16x32_bf16(a[i], b[j], acc[i][j], 0, 0, 0);
    }

    #pragma unroll
    for (int i = 0; i < 4; ++i) {
        size_t row = rowA0 + wm + i * 16 + quad * 4;
        #pragma unroll
        for (int j = 0; j < 4; ++j) {
            size_t col = rowB0 + wn + j * 16 + lm;
            float bv = (EPI == 1) ? bias[col] : 0.0f;
            #pragma unroll
            for (int r = 0; r < 4; ++r) {
                if (EPI == 0)
                    ((bf16*)C)[(row + r) * ldc + col] = __float2bfloat16(acc[i][j][r]);
                else
                    ((float*)C)[(row + r) * ldc + col] = acc[i][j][r] + bv;
            }
        }
    }
}

// ---------------------------------------------------------------- GEMM 256x256, BK=64, 8-wave,
// 8-phase schedule (T1 XCD swizzle + T2 XOR swizzle + T3/T4 counted vmcnt + T5 setprio).
// Derivation/safety invariants:
//  - LDS: A[buf2][half2][128 rows][128B], B same; 128 KiB total. Stage = 1 half-tile/phase
//    (2 global_load_lds x 16B per thread), rotating stream:
//    ph1:Bh1(o) ph2:Bh0(e2) ph3:Bh1(e2) ph4:Ah0(e2) ph5:Ah1(e2) ph6:Bh0(o2) ph7:Ah0(o2) ph8:Ah1(o2)
//  - Reads (one phase ahead of use): ph1:Bn1(e) ph2:Am1(e) ph3:Am0(o) ph4:Bn0(o) ph5:Bn1(o)
//    ph6:Am1(o) ph7:Am0(e2) ph8:Bn0(e2).  Every stage->first-read gap is >= 2 phases.
//  - vmcnt(2) at each phase end  =>  all stages except the current phase's are landed
//    (inductive; VMEM completes in order). lgkmcnt(0) before the 2nd barrier of each phase
//    => a slot's ds_reads are drained before any later phase's DMA overwrites it.
//  - k-accumulation order identical to the m97 kernel (tiles ascending, kh0 then kh1)
//    -> bit-identical numerics.
__global__ __launch_bounds__(512, 2) void gemm_bt8_kernel(
    const bf16* __restrict__ A, const bf16* __restrict__ Bt,
    bf16* __restrict__ C, int K, int ldc) {
    __shared__ __align__(16) char lds[131072];
    char* smA = lds;            // [buf][half][128][128B]
    char* smB = lds + 65536;

    const int tid  = threadIdx.x;
    const int wave = tid >> 6, lane = tid & 63;
    const int lm   = lane & 15, quad = lane >> 4;
    const int wm   = wave >> 2, wn = wave & 3;

    // T1: bijective chunked XCD swizzle (grid % 8 == 0)
    const int id  = blockIdx.x;
    const int q8  = gridDim.x >> 3;
    const int swz = (id & 7) * q8 + (id >> 3);
    const size_t rowA0 = (size_t)(swz & 31) * 256;   // M = 8192 -> 32 m-tiles
    const size_t rowB0 = (size_t)(swz >> 5) * 256;

    // staging: thread -> (row = wave*8 + lane>>3, chunk), global chunk pre-XOR-swizzled
    const int schunk = (lane & 7) ^ (lane >> 3);
    const bf16* pAg = A  + (rowA0 + wave * 8 + (lane >> 3)) * (size_t)K + schunk * 8;
    const bf16* pBg = Bt + (rowB0 + wave * 8 + (lane >> 3)) * (size_t)K + schunk * 8;

    // ds_read bases; chunk XOR matches the staged involution
    const int ch0 = ((quad)     ^ (lm & 7)) * 16;
    const int ch1 = ((quad + 4) ^ (lm & 7)) * 16;
    char* rdA = smA + wm * 16384 + lm * 128;
    char* rdB = smB + (wn >> 1) * 16384 + (wn & 1) * 8192 + lm * 128;

    short8 aX[4][2], aY[4][2], bn0[2][2][2], bn1[2][2];
    floatx4 acc[8][4] = {};

#define STGA(buf, half, toff) do { \
    __builtin_amdgcn_global_load_lds(AS1(pAg + (size_t)((half) * 128 +  0) * K + (toff) * 64), \
        AS3(smA + (buf) * 32768 + (half) * 16384 +    0 + wave * 1024), 16, 0, 0); \
    __builtin_amdgcn_global_load_lds(AS1(pAg + (size_t)((half) * 128 + 64) * K + (toff) * 64), \
        AS3(smA + (buf) * 32768 + (half) * 16384 + 8192 + wave * 1024), 16, 0, 0); \
} while (0)
#define STGB(buf, half, toff) do { \
    __builtin_amdgcn_global_load_lds(AS1(pBg + (size_t)((half) * 128 +  0) * K + (toff) * 64), \
        AS3(smB + (buf) * 32768 + (half) * 16384 +    0 + wave * 1024), 16, 0, 0); \
    __builtin_amdgcn_global_load_lds(AS1(pBg + (size_t)((half) * 128 + 64) * K + (toff) * 64), \
        AS3(smB + (buf) * 32768 + (half) * 16384 + 8192 + wave * 1024), 16, 0, 0); \
} while (0)
#define RDA(buf, mq, d) do { \
    _Pragma("unroll") \
    for (int f_ = 0; f_ < 4; ++f_) { \
        d[f_][0] = *(const short8*)(rdA + (buf) * 32768 + (mq) * 8192 + f_ * 2048 + ch0); \
        d[f_][1] = *(const short8*)(rdA + (buf) * 32768 + (mq) * 8192 + f_ * 2048 + ch1); \
    } \
} while (0)
#define RDB(buf, nq, d) do { \
    _Pragma("unroll") \
    for (int n_ = 0; n_ < 2; ++n_) { \
        d[n_][0] = *(const short8*)(rdB + (buf) * 32768 + (nq) * 4096 + n_ * 2048 + ch0); \
        d[n_][1] = *(const short8*)(rdB + (buf) * 32768 + (nq) * 4096 + n_ * 2048 + ch1); \
    } \
} while (0)
#define MMQ(a, b, mq, nq) do { \
    _Pragma("unroll") \
    for (int f_ = 0; f_ < 4; ++f_) \
        _Pragma("unroll") \
        for (int n_ = 0; n_ < 2; ++n_) { \
            acc[(mq)*4+f_][(nq)*2+n_] = __builtin_amdgcn_mfma_f32_16x16x32_bf16( \
                a[f_][0], b[n_][0], acc[(mq)*4+f_][(nq)*2+n_], 0, 0, 0); \
            acc[(mq)*4+f_][(nq)*2+n_] = __builtin_amdgcn_mfma_f32_16x16x32_bf16( \
                a[f_][1], b[n_][1], acc[(mq)*4+f_][(nq)*2+n_], 0, 0, 0); \
        } \
} while (0)
#define SB0 __builtin_amdgcn_sched_barrier(0)
#define PHASE(RD, ST, MM) do { \
    RD; ST; \
    SB0; __builtin_amdgcn_s_barrier(); SB0; \
    __builtin_amdgcn_s_setprio(1); MM; __builtin_amdgcn_s_setprio(0); SB0; \
    asm volatile("s_waitcnt lgkmcnt(0)" ::: "memory"); \
    asm volatile("s_waitcnt vmcnt(2)" ::: "memory"); \
    SB0; __builtin_amdgcn_s_barrier(); SB0; \
} while (0)

    // prologue: tile0 full, tile1 all but Bh1 (that is iter0-ph1's stage)
    STGA(0, 0, 0); STGA(0, 1, 0); STGB(0, 0, 0); STGB(0, 1, 0);
    STGA(1, 0, 1); STGA(1, 1, 1); STGB(1, 0, 1);
    asm volatile("s_waitcnt vmcnt(0)" ::: "memory");
    SB0; __builtin_amdgcn_s_barrier(); SB0;
    RDA(0, 0, aX); RDB(0, 0, bn0[0]);

    #pragma unroll 1
    for (int i = 0; i < (K / 128) - 1; ++i) {
        PHASE( RDB(0, 1, bn1),    STGB(1, 1, 1), MMQ(aX, bn0[0], 0, 0) ); // ph1
        PHASE( RDA(0, 1, aY),     STGB(0, 0, 2), MMQ(aX, bn1,    0, 1) ); // ph2
        PHASE( RDA(1, 0, aX),     STGB(0, 1, 2), MMQ(aY, bn1,    1, 1) ); // ph3
        PHASE( RDB(1, 0, bn0[1]), STGA(0, 0, 2), MMQ(aY, bn0[0], 1, 0) ); // ph4
        PHASE( RDB(1, 1, bn1),    STGA(0, 1, 2), MMQ(aX, bn0[1], 0, 0) ); // ph5
        PHASE( RDA(1, 1, aY),     STGB(1, 0, 3), MMQ(aX, bn1,    0, 1) ); // ph6
        PHASE( RDA(0, 0, aX),     STGA(1, 0, 3), MMQ(aY, bn1,    1, 1) ); // ph7
        PHASE( RDB(0, 0, bn0[0]), STGA(1, 1, 3), MMQ(aY, bn0[1], 1, 0) ); // ph8
        pAg += 128; pBg += 128;
    }

    // last iteration: only missing stage is Bh1(last); then drain and run dependency-ordered
    RDB(0, 1, bn1); STGB(1, 1, 1);
    SB0; __builtin_amdgcn_s_barrier(); SB0;
    __builtin_amdgcn_s_setprio(1); MMQ(aX, bn0[0], 0, 0); __builtin_amdgcn_s_setprio(0); SB0;
    asm volatile("s_waitcnt lgkmcnt(0)" ::: "memory");
    asm volatile("s_waitcnt vmcnt(0)" ::: "memory");
    SB0; __builtin_amdgcn_s_barrier(); SB0;
    RDA(0, 1, aY);      MMQ(aX, bn1,    0, 1);
    RDA(1, 0, aX);      MMQ(aY, bn1,    1, 1);
    RDB(1, 0, bn0[1]);  MMQ(aY, bn0[0], 1, 0);
    RDB(1, 1, bn1);     MMQ(aX, bn0[1], 0, 0);
    RDA(1, 1, aY);      MMQ(aX, bn1,    0, 1);
    MMQ(aY, bn1,    1, 1);
    MMQ(aY, bn0[1], 1, 0);

    // epilogue: C/D layout row = quad*4 + r, col = lm
    #pragma unroll
    for (int mf = 0; mf < 8; ++mf) {
        size_t row = rowA0 + wm * 128 + mf * 16 + quad * 4;
        #pragma unroll
        for (int nf = 0; nf < 4; ++nf) {
            size_t col = rowB0 + wn * 64 + nf * 16 + lm;
            #pragma unroll
            for (int r = 0; r < 4; ++r)
                C[(row + r) * ldc + col] = __float2bfloat16(acc[mf][nf][r]);
        }
    }
#undef STGA
#undef STGB
#undef RDA
#undef RDB
#undef MMQ
#undef SB0
#undef PHASE
}

// ---------------------------------------------------------------- V -> Vt[b,h,hd,s]
__global__ void transpose_v_kernel(const bf16* __restrict__ qkv, bf16* __restrict__ vt) {
    __shared__ __align__(16) bf16 tile[64][72];
    const int st = blockIdx.x;
    const int bh = blockIdx.y;
    const int b = bh >> 4, h = bh & 15;
    const int s0 = st * 64;
    const int tid = threadIdx.x;
    {
        const int sl = tid >> 2, hc = (tid & 3) * 16;
        const bf16* src = qkv + ((size_t)(b * SS + s0 + sl)) * 3072 + 2048 + h * 64 + hc;
        *(short8*)&tile[sl][hc]     = *(const short8*)src;
        *(short8*)&tile[sl][hc + 8] = *(const short8*)(src + 8);
    }
    __syncthreads();
    {
        const int hl = tid >> 2, sc = (tid & 3) * 16;
        bf16 o[16] __attribute__((aligned(16)));
        #pragma unroll
        for (int i = 0; i < 16; ++i) o[i] = tile[sc + i][hl];
        bf16* dst = vt + ((size_t)(bh * 64 + hl)) * SS + s0 + sc;
        *(short8*)dst       = *(short8*)&o[0];
        *(short8*)(dst + 8) = *(short8*)&o[8];
    }
}

// ---------------------------------------------------------------- causal flash attention v7
// (unchanged from R1: grid 1024, 3 blocks/CU, heavy-first dispatch, single-barrier dbuf)
#define PSTR 68
__global__ __launch_bounds__(256, 3) void flash_attn_kernel(
    const bf16* __restrict__ qkv, const bf16* __restrict__ vt, bf16* __restrict__ ctx) {
    __shared__ __align__(16) bf16 Ks[2][64 * 64];       // double-buffered K tile
    __shared__ __align__(16) bf16 Vs[2][64 * 64];       // double-buffered V tile
    __shared__ __align__(16) bf16 Pl[4][32 * PSTR + 8]; // per-wave P (C->A layout)
    const int tid  = threadIdx.x;
    const int wave = tid >> 6, lane = tid & 63;
    const int lm   = lane & 15, quad = lane >> 4;

    const int id  = blockIdx.x;          // 0..1023
    const int jl  = (id >> 3) & 7;
    const int bh  = (id & 7) * 8 + jl;
    const int p   = 15 - (id >> 6);      // q-tile index, heavy first
    const int b = bh >> 4, h = bh & 15;

    const int lane8r = lane >> 3;        // == row & 7
    const int schunk = (lane & 7) ^ lane8r;

    const bf16* kg = qkv + (size_t)b * SS * 3072 + 1024 + h * 64 + schunk * 8;
    const bf16* vg = vt + (size_t)(b * NH + h) * 64 * SS + schunk * 8;

    bf16* Pw = &Pl[wave][0];

    const int qb = p * 128 + wave * 32;      // wave's first q row
    const int nkt = 2 * p + 2;

    short8 bq[2][2];
    #pragma unroll
    for (int g = 0; g < 2; ++g) {
        const bf16* qp = qkv + ((size_t)(b * SS + qb + g * 16 + lm)) * 3072 + h * 64 + quad * 8;
        bq[g][0] = *(const short8*)qp;
        bq[g][1] = *(const short8*)(qp + 32);
    }

    floatx4 o[2][4] = {};
    float lsum[2] = {0.f, 0.f};

    #pragma unroll
    for (int c = 0; c < 2; ++c) {
        const int row = c * 32 + wave * 8 + lane8r;
        __builtin_amdgcn_global_load_lds(AS1(kg + (size_t)row * 3072), AS3(&Ks[0][(c * 256 + wave * 64) * 8]), 16, 0, 0);
        __builtin_amdgcn_global_load_lds(AS1(vg + (size_t)row * SS), AS3(&Vs[0][(c * 256 + wave * 64) * 8]), 16, 0, 0);
    }

    #pragma unroll 1
    for (int kt = 0; kt < nkt; ++kt) {
        const int cur = kt & 1;
        __syncthreads();   // tile kt arrived (vmcnt drain); buf^1 readers done
        if (kt + 1 < nkt) {
            #pragma unroll
            for (int c = 0; c < 2; ++c) {
                const int row = c * 32 + wave * 8 + lane8r;
                __builtin_amdgcn_global_load_lds(AS1(kg + (size_t)((kt + 1) * 64 + row) * 3072),
                                                 AS3(&Ks[cur ^ 1][(c * 256 + wave * 64) * 8]), 16, 0, 0);
                __builtin_amdgcn_global_load_lds(AS1(vg + (size_t)row * SS + (kt + 1) * 64),
                                                 AS3(&Vs[cur ^ 1][(c * 256 + wave * 64) * 8]), 16, 0, 0);
            }
        }

        const int sw = lm & 7;
        const bf16* Ksb = &Ks[cur][0];
        const bf16* Vsb = &Vs[cur][0];
        short8 ka[4][2], va[4][2];
        #pragma unroll
        for (int nt = 0; nt < 4; ++nt) {
            const int r0 = (nt * 16 + lm) * 64;
            ka[nt][0] = *(const short8*)(Ksb + r0 + ((quad ^ sw) * 8));
            ka[nt][1] = *(const short8*)(Ksb + r0 + (((4 + quad) ^ sw) * 8));
            va[nt][0] = *(const short8*)(Vsb + r0 + ((quad ^ sw) * 8));
            va[nt][1] = *(const short8*)(Vsb + r0 + (((4 + quad) ^ sw) * 8));
        }

        #pragma unroll
        for (int g = 0; g < 2; ++g) {
            floatx4 sc[4];
            #pragma unroll
            for (int nt = 0; nt < 4; ++nt) {
                floatx4 z = {};
                z = __builtin_amdgcn_mfma_f32_16x16x32_bf16(ka[nt][0], bq[g][0], z, 0, 0, 0);
                z = __builtin_amdgcn_mfma_f32_16x16x32_bf16(ka[nt][1], bq[g][1], z, 0, 0, 0);
                sc[nt] = z;
            }
            if (kt * 64 + 63 > qb + g * 16) {
                const int qrow = qb + g * 16 + lm;
                #pragma unroll
                for (int nt = 0; nt < 4; ++nt)
                    #pragma unroll
                    for (int r = 0; r < 4; ++r)
                        if (kt * 64 + nt * 16 + quad * 4 + r > qrow) sc[nt][r] = -1e30f;
            }
            #pragma unroll
            for (int nt = 0; nt < 4; ++nt) {
                bf16 pk[4] __attribute__((aligned(8)));
                #pragma unroll
                for (int r = 0; r < 4; ++r) {
                    float pv = __builtin_amdgcn_exp2f(sc[nt][r] * 0.18033688f);
                    lsum[g] += pv;
                    pk[r] = __float2bfloat16(pv);
                }
                *(uint64_t*)&Pw[(g * 16 + lm) * PSTR + nt * 16 + quad * 4] = *(uint64_t*)pk;
            }
        }
        #pragma unroll
        for (int g = 0; g < 2; ++g) {
            const short8 ap0 = *(const short8*)&Pw[(g * 16 + lm) * PSTR + quad * 8];
            const short8 ap1 = *(const short8*)&Pw[(g * 16 + lm) * PSTR + 32 + quad * 8];
            #pragma unroll
            for (int t = 0; t < 4; ++t) {
                o[g][t] = __builtin_amdgcn_mfma_f32_16x16x32_bf16(ap0, va[t][0], o[g][t], 0, 0, 0);
                o[g][t] = __builtin_amdgcn_mfma_f32_16x16x32_bf16(ap1, va[t][1], o[g][t], 0, 0, 0);
            }
        }
    }

    #pragma unroll
    for (int g = 0; g < 2; ++g) {
        float rsum = lsum[g];
        rsum += __shfl_xor(rsum, 16);
        rsum += __shfl_xor(rsum, 32);
        float rl[4];
        #pragma unroll
        for (int r = 0; r < 4; ++r) rl[r] = 1.0f / __shfl(rsum, quad * 4 + r);
        #pragma unroll
        for (int t = 0; t < 4; ++t)
            #pragma unroll
            for (int r = 0; r < 4; ++r) {
                size_t row = (size_t)b * SS + qb + g * 16 + quad * 4 + r;
                ctx[row * 1024 + h * 64 + t * 16 + lm] = __float2bfloat16(o[g][t][r] * rl[r]);
            }
    }
}

// ---------------------------------------------------------------- launch
extern "C" void kernel_launch(void* const* d_in, const int* in_sizes, int n_in,
                              void* d_out, int out_size, void* d_ws, size_t ws_size,
                              hipStream_t stream) {
    const float* x  = (const float*)d_in[0];
    const float* Wq = (const float*)d_in[1];
    const float* Wk = (const float*)d_in[2];
    const float* Wv = (const float*)d_in[3];
    const float* Wo = (const float*)d_in[4];
    const float* bo = (const float*)d_in[5];

    char* ws = (char*)d_ws;
    bf16* xb  = (bf16*)ws;  ws += (size_t)8192 * 1024 * 2;   // 16 MB (reused as ctx)
    bf16* wt  = (bf16*)ws;  ws += (size_t)3072 * 1024 * 2;   //  6 MB
    bf16* wob = (bf16*)ws;  ws += (size_t)1024 * 1024 * 2;   //  2 MB
    bf16* qkv = (bf16*)ws;  ws += (size_t)8192 * 3072 * 2;   // 48 MB
    bf16* vtb = (bf16*)ws;  ws += (size_t)BB * NH * HDIM * SS * 2;  // 16 MB
    bf16* ctx = xb;  // xb dead after gemm_qkv -> alias

    cast_f32_bf16_kernel<<<4096, 256, 0, stream>>>(x, xb);
    prep_wqkv_kernel<<<dim3(16, 48), 256, 0, stream>>>(Wq, Wk, Wv, wt);
    cast_f32_bf16_kernel<<<512, 256, 0, stream>>>(Wo, wob);
    gemm_bt8_kernel<<<384, 512, 0, stream>>>(xb, wt, qkv, 1024, 3072);
    transpose_v_kernel<<<dim3(32, 64), 256, 0, stream>>>(qkv, vtb);
    flash_attn_kernel<<<1024, 256, 0, stream>>>(qkv, vtb, ctx);
    gemm_bt_kernel<1><<<dim3(64, 8), 256, 0, stream>>>(ctx, wob, d_out, bo, 1024, 1024);
}

// Round 5
// 262.554 us; speedup vs baseline: 1.2334x; 1.2334x over previous
//
#include <hip/hip_runtime.h>
#include <hip/hip_bf16.h>

// Problem constants
#define BB   4
#define SS   2048
#define DIN  1024
#define DOUT 1024
#define NH   16
#define HDIM 64

typedef __hip_bfloat16 bf16;
typedef __attribute__((ext_vector_type(8))) short short8;   // bf16 MFMA A/B frag (4 VGPR)
typedef __attribute__((ext_vector_type(4))) float floatx4;  // MFMA C/D frag

#define AS1(p) ((const __attribute__((address_space(1))) void*)(p))
#define AS3(p) ((__attribute__((address_space(3))) void*)(p))

// ---------------------------------------------------------------- fused prep:
// bid [0,4096)      : cast x (f32 -> bf16), 8 elems/thread
// bid [4096,4864)   : build Wqkv^T tile (64x64 transpose + cast)
// bid [4864,5376)   : cast Wo (f32 -> bf16)
// Merging 3 tiny kernels into 1 removes 2 launch gaps (~10 us each measured as the
// R1 sum-of-parts vs total discrepancy).
__global__ void prep_all_kernel(const float* __restrict__ x,
                                const float* __restrict__ Wq, const float* __restrict__ Wk,
                                const float* __restrict__ Wv, const float* __restrict__ Wo,
                                bf16* __restrict__ xb, bf16* __restrict__ wt,
                                bf16* __restrict__ wob) {
    __shared__ float tile[64][65];
    const int bid = blockIdx.x;
    const int tid = threadIdx.x;
    if (bid < 4096 || bid >= 4864) {
        const float* src = (bid < 4096) ? x : Wo;
        bf16* dst        = (bid < 4096) ? xb : wob;
        const int  rb    = (bid < 4096) ? bid : (bid - 4864);
        size_t i = ((size_t)rb * 256 + tid) * 8;
        float4 a = *(const float4*)(src + i);
        float4 b = *(const float4*)(src + i + 4);
        bf16 o[8] __attribute__((aligned(16)));
        o[0] = __float2bfloat16(a.x); o[1] = __float2bfloat16(a.y);
        o[2] = __float2bfloat16(a.z); o[3] = __float2bfloat16(a.w);
        o[4] = __float2bfloat16(b.x); o[5] = __float2bfloat16(b.y);
        o[6] = __float2bfloat16(b.z); o[7] = __float2bfloat16(b.w);
        *(short8*)(dst + i) = *(short8*)o;
        return;
    }
    // ---- prep Wqkv^T: rows = output col n, cols = k ----
    const int pb = bid - 4096;
    const int kt = pb & 15;             // 16 k-tiles
    const int nt = pb >> 4;             // 48 n-tiles
    const int k0 = kt * 64, n0 = nt * 64;
    const float* W = (n0 < 1024) ? Wq : (n0 < 2048 ? Wk : Wv);
    const int col0 = n0 & 1023;
    {
        const int kl = tid >> 2, nc = (tid & 3) * 16;
        const float* src = W + (size_t)(k0 + kl) * 1024 + col0 + nc;
        #pragma unroll
        for (int i = 0; i < 16; i += 4) {
            float4 v = *(const float4*)(src + i);
            tile[kl][nc + i + 0] = v.x; tile[kl][nc + i + 1] = v.y;
            tile[kl][nc + i + 2] = v.z; tile[kl][nc + i + 3] = v.w;
        }
    }
    __syncthreads();
    {
        const int nl = tid >> 2, kc = (tid & 3) * 16;
        bf16 o[16] __attribute__((aligned(16)));
        #pragma unroll
        for (int i = 0; i < 16; ++i) o[i] = __float2bfloat16(tile[kc + i][nl]);
        bf16* dst = wt + (size_t)(n0 + nl) * 1024 + k0 + kc;
        *(short8*)dst       = *(short8*)&o[0];
        *(short8*)(dst + 8) = *(short8*)&o[8];
    }
}

// ---------------------------------------------------------------- GEMM: C = A @ Bt^T
// m97 structure — PROVEN correct/fast in R0/R1 (655 TF at this shape). R2-R4's custom
// counted-vmcnt schedules either spilled (R2) or raced (R3/R4, m152's lesson) — reverted.
// NEW (low-risk): for EPI==0, blocks computing the V-part of qkv (rowB0 >= 2048,
// block-uniform) write their accumulators TRANSPOSED straight into vt[b,h,hd,s] as 8B
// column chunks (acc[i][j][0..3] = 4 consecutive s values) and skip the dead qkv V-store.
// This deletes the standalone transpose kernel (one launch + 32 MB HBM traffic).
template<int EPI>
__global__ __launch_bounds__(256) void gemm_bt_kernel(
    const bf16* __restrict__ A, const bf16* __restrict__ Bt,
    void* __restrict__ C, const float* __restrict__ bias, int K, int ldc,
    bf16* __restrict__ vt) {
    __shared__ __align__(16) bf16 As[128][32];
    __shared__ __align__(16) bf16 Bs[128][32];
    const int tid  = threadIdx.x;
    const int wave = tid >> 6, lane = tid & 63;
    const int lm   = lane & 15, quad = lane >> 4;
    const int wm   = (wave >> 1) * 64, wn = (wave & 1) * 64;
    const size_t rowA0 = (size_t)blockIdx.x * 128;
    const size_t rowB0 = (size_t)blockIdx.y * 128;
    const int srow = wave * 16 + (lane >> 2);
    const int skc  = (lane & 3) * 8;

    floatx4 acc[4][4] = {};

    for (int k0 = 0; k0 < K; k0 += 32) {
        __syncthreads();
        #pragma unroll
        for (int r = 0; r < 2; ++r) {
            const bf16* gA = A  + (rowA0 + r * 64 + srow) * (size_t)K + k0 + skc;
            __builtin_amdgcn_global_load_lds(AS1(gA), AS3(&As[r * 64 + wave * 16][0]), 16, 0, 0);
            const bf16* gB = Bt + (rowB0 + r * 64 + srow) * (size_t)K + k0 + skc;
            __builtin_amdgcn_global_load_lds(AS1(gB), AS3(&Bs[r * 64 + wave * 16][0]), 16, 0, 0);
        }
        __syncthreads();
        short8 a[4], b[4];
        #pragma unroll
        for (int i = 0; i < 4; ++i) a[i] = *(const short8*)&As[wm + i * 16 + lm][quad * 8];
        #pragma unroll
        for (int j = 0; j < 4; ++j) b[j] = *(const short8*)&Bs[wn + j * 16 + lm][quad * 8];
        #pragma unroll
        for (int i = 0; i < 4; ++i)
            #pragma unroll
            for (int j = 0; j < 4; ++j)
                acc[i][j] = __builtin_amdgcn_mfma_f32_16x16x32_bf16(a[i], b[j], acc[i][j], 0, 0, 0);
    }

    if (EPI == 0 && rowB0 >= 2048) {
        // V-part: write transposed into vt[((b*16+h)*64+hd)*SS + s]; skip dead qkv store.
        #pragma unroll
        for (int i = 0; i < 4; ++i) {
            size_t row = rowA0 + wm + i * 16 + quad * 4;   // = b*2048 + s, 4-aligned
            const size_t b = row >> 11;
            const int    s = (int)(row & 2047);
            #pragma unroll
            for (int j = 0; j < 4; ++j) {
                const int col = (int)(rowB0 - 2048) + wn + j * 16 + lm;   // h*64 + hd
                bf16 o[4] __attribute__((aligned(8)));
                #pragma unroll
                for (int r = 0; r < 4; ++r) o[r] = __float2bfloat16(acc[i][j][r]);
                *(uint64_t*)(vt + ((b * 16 + (col >> 6)) * 64 + (col & 63)) * (size_t)SS + s)
                    = *(uint64_t*)o;
            }
        }
        return;
    }

    #pragma unroll
    for (int i = 0; i < 4; ++i) {
        size_t row = rowA0 + wm + i * 16 + quad * 4;
        #pragma unroll
        for (int j = 0; j < 4; ++j) {
            size_t col = rowB0 + wn + j * 16 + lm;
            float bv = (EPI == 1) ? bias[col] : 0.0f;
            #pragma unroll
            for (int r = 0; r < 4; ++r) {
                if (EPI == 0)
                    ((bf16*)C)[(row + r) * ldc + col] = __float2bfloat16(acc[i][j][r]);
                else
                    ((float*)C)[(row + r) * ldc + col] = acc[i][j][r] + bv;
            }
        }
    }
}

// ---------------------------------------------------------------- causal flash attention v7
// (unchanged from R1: grid 1024, 3 blocks/CU, heavy-first dispatch, single-barrier dbuf)
#define PSTR 68
__global__ __launch_bounds__(256, 3) void flash_attn_kernel(
    const bf16* __restrict__ qkv, const bf16* __restrict__ vt, bf16* __restrict__ ctx) {
    __shared__ __align__(16) bf16 Ks[2][64 * 64];       // double-buffered K tile
    __shared__ __align__(16) bf16 Vs[2][64 * 64];       // double-buffered V tile
    __shared__ __align__(16) bf16 Pl[4][32 * PSTR + 8]; // per-wave P (C->A layout)
    const int tid  = threadIdx.x;
    const int wave = tid >> 6, lane = tid & 63;
    const int lm   = lane & 15, quad = lane >> 4;

    const int id  = blockIdx.x;          // 0..1023
    const int jl  = (id >> 3) & 7;
    const int bh  = (id & 7) * 8 + jl;
    const int p   = 15 - (id >> 6);      // q-tile index, heavy first
    const int b = bh >> 4, h = bh & 15;

    const int lane8r = lane >> 3;        // == row & 7
    const int schunk = (lane & 7) ^ lane8r;

    const bf16* kg = qkv + (size_t)b * SS * 3072 + 1024 + h * 64 + schunk * 8;
    const bf16* vg = vt + (size_t)(b * NH + h) * 64 * SS + schunk * 8;

    bf16* Pw = &Pl[wave][0];

    const int qb = p * 128 + wave * 32;      // wave's first q row
    const int nkt = 2 * p + 2;

    short8 bq[2][2];
    #pragma unroll
    for (int g = 0; g < 2; ++g) {
        const bf16* qp = qkv + ((size_t)(b * SS + qb + g * 16 + lm)) * 3072 + h * 64 + quad * 8;
        bq[g][0] = *(const short8*)qp;
        bq[g][1] = *(const short8*)(qp + 32);
    }

    floatx4 o[2][4] = {};
    float lsum[2] = {0.f, 0.f};

    #pragma unroll
    for (int c = 0; c < 2; ++c) {
        const int row = c * 32 + wave * 8 + lane8r;
        __builtin_amdgcn_global_load_lds(AS1(kg + (size_t)row * 3072), AS3(&Ks[0][(c * 256 + wave * 64) * 8]), 16, 0, 0);
        __builtin_amdgcn_global_load_lds(AS1(vg + (size_t)row * SS), AS3(&Vs[0][(c * 256 + wave * 64) * 8]), 16, 0, 0);
    }

    #pragma unroll 1
    for (int kt = 0; kt < nkt; ++kt) {
        const int cur = kt & 1;
        __syncthreads();   // tile kt arrived (vmcnt drain); buf^1 readers done
        if (kt + 1 < nkt) {
            #pragma unroll
            for (int c = 0; c < 2; ++c) {
                const int row = c * 32 + wave * 8 + lane8r;
                __builtin_amdgcn_global_load_lds(AS1(kg + (size_t)((kt + 1) * 64 + row) * 3072),
                                                 AS3(&Ks[cur ^ 1][(c * 256 + wave * 64) * 8]), 16, 0, 0);
                __builtin_amdgcn_global_load_lds(AS1(vg + (size_t)row * SS + (kt + 1) * 64),
                                                 AS3(&Vs[cur ^ 1][(c * 256 + wave * 64) * 8]), 16, 0, 0);
            }
        }

        const int sw = lm & 7;
        const bf16* Ksb = &Ks[cur][0];
        const bf16* Vsb = &Vs[cur][0];
        short8 ka[4][2], va[4][2];
        #pragma unroll
        for (int nt = 0; nt < 4; ++nt) {
            const int r0 = (nt * 16 + lm) * 64;
            ka[nt][0] = *(const short8*)(Ksb + r0 + ((quad ^ sw) * 8));
            ka[nt][1] = *(const short8*)(Ksb + r0 + (((4 + quad) ^ sw) * 8));
            va[nt][0] = *(const short8*)(Vsb + r0 + ((quad ^ sw) * 8));
            va[nt][1] = *(const short8*)(Vsb + r0 + (((4 + quad) ^ sw) * 8));
        }

        #pragma unroll
        for (int g = 0; g < 2; ++g) {
            floatx4 sc[4];
            #pragma unroll
            for (int nt = 0; nt < 4; ++nt) {
                floatx4 z = {};
                z = __builtin_amdgcn_mfma_f32_16x16x32_bf16(ka[nt][0], bq[g][0], z, 0, 0, 0);
                z = __builtin_amdgcn_mfma_f32_16x16x32_bf16(ka[nt][1], bq[g][1], z, 0, 0, 0);
                sc[nt] = z;
            }
            if (kt * 64 + 63 > qb + g * 16) {
                const int qrow = qb + g * 16 + lm;
                #pragma unroll
                for (int nt = 0; nt < 4; ++nt)
                    #pragma unroll
                    for (int r = 0; r < 4; ++r)
                        if (kt * 64 + nt * 16 + quad * 4 + r > qrow) sc[nt][r] = -1e30f;
            }
            #pragma unroll
            for (int nt = 0; nt < 4; ++nt) {
                bf16 pk[4] __attribute__((aligned(8)));
                #pragma unroll
                for (int r = 0; r < 4; ++r) {
                    float pv = __builtin_amdgcn_exp2f(sc[nt][r] * 0.18033688f);
                    lsum[g] += pv;
                    pk[r] = __float2bfloat16(pv);
                }
                *(uint64_t*)&Pw[(g * 16 + lm) * PSTR + nt * 16 + quad * 4] = *(uint64_t*)pk;
            }
        }
        #pragma unroll
        for (int g = 0; g < 2; ++g) {
            const short8 ap0 = *(const short8*)&Pw[(g * 16 + lm) * PSTR + quad * 8];
            const short8 ap1 = *(const short8*)&Pw[(g * 16 + lm) * PSTR + 32 + quad * 8];
            #pragma unroll
            for (int t = 0; t < 4; ++t) {
                o[g][t] = __builtin_amdgcn_mfma_f32_16x16x32_bf16(ap0, va[t][0], o[g][t], 0, 0, 0);
                o[g][t] = __builtin_amdgcn_mfma_f32_16x16x32_bf16(ap1, va[t][1], o[g][t], 0, 0, 0);
            }
        }
    }

    #pragma unroll
    for (int g = 0; g < 2; ++g) {
        float rsum = lsum[g];
        rsum += __shfl_xor(rsum, 16);
        rsum += __shfl_xor(rsum, 32);
        float rl[4];
        #pragma unroll
        for (int r = 0; r < 4; ++r) rl[r] = 1.0f / __shfl(rsum, quad * 4 + r);
        #pragma unroll
        for (int t = 0; t < 4; ++t)
            #pragma unroll
            for (int r = 0; r < 4; ++r) {
                size_t row = (size_t)b * SS + qb + g * 16 + quad * 4 + r;
                ctx[row * 1024 + h * 64 + t * 16 + lm] = __float2bfloat16(o[g][t][r] * rl[r]);
            }
    }
}

// ---------------------------------------------------------------- launch (4 dispatches)
extern "C" void kernel_launch(void* const* d_in, const int* in_sizes, int n_in,
                              void* d_out, int out_size, void* d_ws, size_t ws_size,
                              hipStream_t stream) {
    const float* x  = (const float*)d_in[0];
    const float* Wq = (const float*)d_in[1];
    const float* Wk = (const float*)d_in[2];
    const float* Wv = (const float*)d_in[3];
    const float* Wo = (const float*)d_in[4];
    const float* bo = (const float*)d_in[5];

    char* ws = (char*)d_ws;
    bf16* xb  = (bf16*)ws;  ws += (size_t)8192 * 1024 * 2;   // 16 MB (reused as ctx)
    bf16* wt  = (bf16*)ws;  ws += (size_t)3072 * 1024 * 2;   //  6 MB
    bf16* wob = (bf16*)ws;  ws += (size_t)1024 * 1024 * 2;   //  2 MB
    bf16* qkv = (bf16*)ws;  ws += (size_t)8192 * 3072 * 2;   // 48 MB (V third dead/unwritten)
    bf16* vtb = (bf16*)ws;  ws += (size_t)BB * NH * HDIM * SS * 2;  // 16 MB
    bf16* ctx = xb;  // xb dead after gemm_qkv -> alias

    prep_all_kernel<<<5376, 256, 0, stream>>>(x, Wq, Wk, Wv, Wo, xb, wt, wob);
    gemm_bt_kernel<0><<<dim3(64, 24), 256, 0, stream>>>(xb, wt, (void*)qkv, nullptr, 1024, 3072, vtb);
    flash_attn_kernel<<<1024, 256, 0, stream>>>(qkv, vtb, ctx);
    gemm_bt_kernel<1><<<dim3(64, 8), 256, 0, stream>>>(ctx, wob, d_out, bo, 1024, 1024, nullptr);
}

// Round 6
// 252.011 us; speedup vs baseline: 1.2850x; 1.0418x over previous
//
#include <hip/hip_runtime.h>
#include <hip/hip_bf16.h>

// Problem constants
#define BB   4
#define SS   2048
#define DIN  1024
#define DOUT 1024
#define NH   16
#define HDIM 64

typedef __hip_bfloat16 bf16;
typedef __attribute__((ext_vector_type(8))) short short8;   // bf16 MFMA A/B frag (4 VGPR)
typedef __attribute__((ext_vector_type(4))) float floatx4;  // MFMA C/D frag

#define AS1(p) ((const __attribute__((address_space(1))) void*)(p))
#define AS3(p) ((__attribute__((address_space(3))) void*)(p))

// ---------------------------------------------------------------- fused prep:
// bid [0,4096)      : cast x (f32 -> bf16), 8 elems/thread
// bid [4096,4864)   : build Wqkv^T tile (64x64 transpose + cast)
// bid [4864,5376)   : cast Wo (f32 -> bf16)
__global__ void prep_all_kernel(const float* __restrict__ x,
                                const float* __restrict__ Wq, const float* __restrict__ Wk,
                                const float* __restrict__ Wv, const float* __restrict__ Wo,
                                bf16* __restrict__ xb, bf16* __restrict__ wt,
                                bf16* __restrict__ wob) {
    __shared__ float tile[64][65];
    const int bid = blockIdx.x;
    const int tid = threadIdx.x;
    if (bid < 4096 || bid >= 4864) {
        const float* src = (bid < 4096) ? x : Wo;
        bf16* dst        = (bid < 4096) ? xb : wob;
        const int  rb    = (bid < 4096) ? bid : (bid - 4864);
        size_t i = ((size_t)rb * 256 + tid) * 8;
        float4 a = *(const float4*)(src + i);
        float4 b = *(const float4*)(src + i + 4);
        bf16 o[8] __attribute__((aligned(16)));
        o[0] = __float2bfloat16(a.x); o[1] = __float2bfloat16(a.y);
        o[2] = __float2bfloat16(a.z); o[3] = __float2bfloat16(a.w);
        o[4] = __float2bfloat16(b.x); o[5] = __float2bfloat16(b.y);
        o[6] = __float2bfloat16(b.z); o[7] = __float2bfloat16(b.w);
        *(short8*)(dst + i) = *(short8*)o;
        return;
    }
    // ---- prep Wqkv^T: rows = output col n, cols = k ----
    const int pb = bid - 4096;
    const int kt = pb & 15;             // 16 k-tiles
    const int nt = pb >> 4;             // 48 n-tiles
    const int k0 = kt * 64, n0 = nt * 64;
    const float* W = (n0 < 1024) ? Wq : (n0 < 2048 ? Wk : Wv);
    const int col0 = n0 & 1023;
    {
        const int kl = tid >> 2, nc = (tid & 3) * 16;
        const float* src = W + (size_t)(k0 + kl) * 1024 + col0 + nc;
        #pragma unroll
        for (int i = 0; i < 16; i += 4) {
            float4 v = *(const float4*)(src + i);
            tile[kl][nc + i + 0] = v.x; tile[kl][nc + i + 1] = v.y;
            tile[kl][nc + i + 2] = v.z; tile[kl][nc + i + 3] = v.w;
        }
    }
    __syncthreads();
    {
        const int nl = tid >> 2, kc = (tid & 3) * 16;
        bf16 o[16] __attribute__((aligned(16)));
        #pragma unroll
        for (int i = 0; i < 16; ++i) o[i] = __float2bfloat16(tile[kc + i][nl]);
        bf16* dst = wt + (size_t)(n0 + nl) * 1024 + k0 + kc;
        *(short8*)dst       = *(short8*)&o[0];
        *(short8*)(dst + 8) = *(short8*)&o[8];
    }
}

// ---------------------------------------------------------------- GEMM: C = A @ Bt^T
// m97 2-barrier structure (PROVEN R0/R1/R5) with two in-template upgrades (R6):
//  - BK=64: halves the per-K-step barrier+vmcnt(0) drain count (16 iters, 32 MFMA/drain).
//  - XOR chunk swizzle (rule #21, same involution as the flash kernel): linear gload_lds
//    dest + pre-swizzled GLOBAL source chunk ((lane&7)^(lane>>3)) + swizzled ds_read
//    chunk (c ^ (row&7)). Kills the 8/16-way ds_read_b128 bank conflict (6.29M measured).
// Accumulation k-order identical to BK=32 version (two half-K MFMAs in ascending order)
// -> bit-identical numerics. No custom waitcnt: __syncthreads provides the full drain.
// EPI==0 && rowB0>=2048: V-part written transposed straight to vt (R5 fusion, proven).
template<int EPI>
__global__ __launch_bounds__(256) void gemm_bt_kernel(
    const bf16* __restrict__ A, const bf16* __restrict__ Bt,
    void* __restrict__ C, const float* __restrict__ bias, int K, int ldc,
    bf16* __restrict__ vt) {
    __shared__ __align__(16) bf16 As[128][64];
    __shared__ __align__(16) bf16 Bs[128][64];
    const int tid  = threadIdx.x;
    const int wave = tid >> 6, lane = tid & 63;
    const int lm   = lane & 15, quad = lane >> 4;
    const int wm   = (wave >> 1) * 64, wn = (wave & 1) * 64;
    const size_t rowA0 = (size_t)blockIdx.x * 128;
    const size_t rowB0 = (size_t)blockIdx.y * 128;

    // staging: wave w, sub-block j: rows (w*4+j)*8 + (lane>>3); LDS dest linear
    // (wave-uniform base + lane*16); global source chunk pre-XOR-swizzled.
    const int srow8  = lane >> 3;            // row within 8-group == row&7
    const int schunk = (lane & 7) ^ srow8;   // source logical chunk
    const int sw     = lm & 7;               // read-side row&7

    floatx4 acc[4][4] = {};

    for (int k0 = 0; k0 < K; k0 += 64) {
        __syncthreads();
        #pragma unroll
        for (int j = 0; j < 4; ++j) {
            const int rbase = (wave * 4 + j) * 8;
            const bf16* gA = A  + (rowA0 + rbase + srow8) * (size_t)K + k0 + schunk * 8;
            __builtin_amdgcn_global_load_lds(AS1(gA), AS3(&As[rbase][0]), 16, 0, 0);
            const bf16* gB = Bt + (rowB0 + rbase + srow8) * (size_t)K + k0 + schunk * 8;
            __builtin_amdgcn_global_load_lds(AS1(gB), AS3(&Bs[rbase][0]), 16, 0, 0);
        }
        __syncthreads();
        short8 a[4][2], b[4][2];
        #pragma unroll
        for (int i = 0; i < 4; ++i) {
            const int r = wm + i * 16 + lm;
            a[i][0] = *(const short8*)&As[r][((quad    ) ^ sw) * 8];
            a[i][1] = *(const short8*)&As[r][((quad + 4) ^ sw) * 8];
        }
        #pragma unroll
        for (int j = 0; j < 4; ++j) {
            const int r = wn + j * 16 + lm;
            b[j][0] = *(const short8*)&Bs[r][((quad    ) ^ sw) * 8];
            b[j][1] = *(const short8*)&Bs[r][((quad + 4) ^ sw) * 8];
        }
        #pragma unroll
        for (int i = 0; i < 4; ++i)
            #pragma unroll
            for (int j = 0; j < 4; ++j) {
                acc[i][j] = __builtin_amdgcn_mfma_f32_16x16x32_bf16(a[i][0], b[j][0], acc[i][j], 0, 0, 0);
                acc[i][j] = __builtin_amdgcn_mfma_f32_16x16x32_bf16(a[i][1], b[j][1], acc[i][j], 0, 0, 0);
            }
    }

    if (EPI == 0 && rowB0 >= 2048) {
        // V-part: write transposed into vt[((b*16+h)*64+hd)*SS + s]; skip dead qkv store.
        #pragma unroll
        for (int i = 0; i < 4; ++i) {
            size_t row = rowA0 + wm + i * 16 + quad * 4;   // = b*2048 + s, 4-aligned
            const size_t b = row >> 11;
            const int    s = (int)(row & 2047);
            #pragma unroll
            for (int j = 0; j < 4; ++j) {
                const int col = (int)(rowB0 - 2048) + wn + j * 16 + lm;   // h*64 + hd
                bf16 o[4] __attribute__((aligned(8)));
                #pragma unroll
                for (int r = 0; r < 4; ++r) o[r] = __float2bfloat16(acc[i][j][r]);
                *(uint64_t*)(vt + ((b * 16 + (col >> 6)) * 64 + (col & 63)) * (size_t)SS + s)
                    = *(uint64_t*)o;
            }
        }
        return;
    }

    #pragma unroll
    for (int i = 0; i < 4; ++i) {
        size_t row = rowA0 + wm + i * 16 + quad * 4;
        #pragma unroll
        for (int j = 0; j < 4; ++j) {
            size_t col = rowB0 + wn + j * 16 + lm;
            float bv = (EPI == 1) ? bias[col] : 0.0f;
            #pragma unroll
            for (int r = 0; r < 4; ++r) {
                if (EPI == 0)
                    ((bf16*)C)[(row + r) * ldc + col] = __float2bfloat16(acc[i][j][r]);
                else
                    ((float*)C)[(row + r) * ldc + col] = acc[i][j][r] + bv;
            }
        }
    }
}

// ---------------------------------------------------------------- causal flash attention v7
// (unchanged from R1: grid 1024, 3 blocks/CU, heavy-first dispatch, single-barrier dbuf)
#define PSTR 68
__global__ __launch_bounds__(256, 3) void flash_attn_kernel(
    const bf16* __restrict__ qkv, const bf16* __restrict__ vt, bf16* __restrict__ ctx) {
    __shared__ __align__(16) bf16 Ks[2][64 * 64];       // double-buffered K tile
    __shared__ __align__(16) bf16 Vs[2][64 * 64];       // double-buffered V tile
    __shared__ __align__(16) bf16 Pl[4][32 * PSTR + 8]; // per-wave P (C->A layout)
    const int tid  = threadIdx.x;
    const int wave = tid >> 6, lane = tid & 63;
    const int lm   = lane & 15, quad = lane >> 4;

    const int id  = blockIdx.x;          // 0..1023
    const int jl  = (id >> 3) & 7;
    const int bh  = (id & 7) * 8 + jl;
    const int p   = 15 - (id >> 6);      // q-tile index, heavy first
    const int b = bh >> 4, h = bh & 15;

    const int lane8r = lane >> 3;        // == row & 7
    const int schunk = (lane & 7) ^ lane8r;

    const bf16* kg = qkv + (size_t)b * SS * 3072 + 1024 + h * 64 + schunk * 8;
    const bf16* vg = vt + (size_t)(b * NH + h) * 64 * SS + schunk * 8;

    bf16* Pw = &Pl[wave][0];

    const int qb = p * 128 + wave * 32;      // wave's first q row
    const int nkt = 2 * p + 2;

    short8 bq[2][2];
    #pragma unroll
    for (int g = 0; g < 2; ++g) {
        const bf16* qp = qkv + ((size_t)(b * SS + qb + g * 16 + lm)) * 3072 + h * 64 + quad * 8;
        bq[g][0] = *(const short8*)qp;
        bq[g][1] = *(const short8*)(qp + 32);
    }

    floatx4 o[2][4] = {};
    float lsum[2] = {0.f, 0.f};

    #pragma unroll
    for (int c = 0; c < 2; ++c) {
        const int row = c * 32 + wave * 8 + lane8r;
        __builtin_amdgcn_global_load_lds(AS1(kg + (size_t)row * 3072), AS3(&Ks[0][(c * 256 + wave * 64) * 8]), 16, 0, 0);
        __builtin_amdgcn_global_load_lds(AS1(vg + (size_t)row * SS), AS3(&Vs[0][(c * 256 + wave * 64) * 8]), 16, 0, 0);
    }

    #pragma unroll 1
    for (int kt = 0; kt < nkt; ++kt) {
        const int cur = kt & 1;
        __syncthreads();   // tile kt arrived (vmcnt drain); buf^1 readers done
        if (kt + 1 < nkt) {
            #pragma unroll
            for (int c = 0; c < 2; ++c) {
                const int row = c * 32 + wave * 8 + lane8r;
                __builtin_amdgcn_global_load_lds(AS1(kg + (size_t)((kt + 1) * 64 + row) * 3072),
                                                 AS3(&Ks[cur ^ 1][(c * 256 + wave * 64) * 8]), 16, 0, 0);
                __builtin_amdgcn_global_load_lds(AS1(vg + (size_t)row * SS + (kt + 1) * 64),
                                                 AS3(&Vs[cur ^ 1][(c * 256 + wave * 64) * 8]), 16, 0, 0);
            }
        }

        const int sw = lm & 7;
        const bf16* Ksb = &Ks[cur][0];
        const bf16* Vsb = &Vs[cur][0];
        short8 ka[4][2], va[4][2];
        #pragma unroll
        for (int nt = 0; nt < 4; ++nt) {
            const int r0 = (nt * 16 + lm) * 64;
            ka[nt][0] = *(const short8*)(Ksb + r0 + ((quad ^ sw) * 8));
            ka[nt][1] = *(const short8*)(Ksb + r0 + (((4 + quad) ^ sw) * 8));
            va[nt][0] = *(const short8*)(Vsb + r0 + ((quad ^ sw) * 8));
            va[nt][1] = *(const short8*)(Vsb + r0 + (((4 + quad) ^ sw) * 8));
        }

        #pragma unroll
        for (int g = 0; g < 2; ++g) {
            floatx4 sc[4];
            #pragma unroll
            for (int nt = 0; nt < 4; ++nt) {
                floatx4 z = {};
                z = __builtin_amdgcn_mfma_f32_16x16x32_bf16(ka[nt][0], bq[g][0], z, 0, 0, 0);
                z = __builtin_amdgcn_mfma_f32_16x16x32_bf16(ka[nt][1], bq[g][1], z, 0, 0, 0);
                sc[nt] = z;
            }
            if (kt * 64 + 63 > qb + g * 16) {
                const int qrow = qb + g * 16 + lm;
                #pragma unroll
                for (int nt = 0; nt < 4; ++nt)
                    #pragma unroll
                    for (int r = 0; r < 4; ++r)
                        if (kt * 64 + nt * 16 + quad * 4 + r > qrow) sc[nt][r] = -1e30f;
            }
            #pragma unroll
            for (int nt = 0; nt < 4; ++nt) {
                bf16 pk[4] __attribute__((aligned(8)));
                #pragma unroll
                for (int r = 0; r < 4; ++r) {
                    float pv = __builtin_amdgcn_exp2f(sc[nt][r] * 0.18033688f);
                    lsum[g] += pv;
                    pk[r] = __float2bfloat16(pv);
                }
                *(uint64_t*)&Pw[(g * 16 + lm) * PSTR + nt * 16 + quad * 4] = *(uint64_t*)pk;
            }
        }
        #pragma unroll
        for (int g = 0; g < 2; ++g) {
            const short8 ap0 = *(const short8*)&Pw[(g * 16 + lm) * PSTR + quad * 8];
            const short8 ap1 = *(const short8*)&Pw[(g * 16 + lm) * PSTR + 32 + quad * 8];
            #pragma unroll
            for (int t = 0; t < 4; ++t) {
                o[g][t] = __builtin_amdgcn_mfma_f32_16x16x32_bf16(ap0, va[t][0], o[g][t], 0, 0, 0);
                o[g][t] = __builtin_amdgcn_mfma_f32_16x16x32_bf16(ap1, va[t][1], o[g][t], 0, 0, 0);
            }
        }
    }

    #pragma unroll
    for (int g = 0; g < 2; ++g) {
        float rsum = lsum[g];
        rsum += __shfl_xor(rsum, 16);
        rsum += __shfl_xor(rsum, 32);
        float rl[4];
        #pragma unroll
        for (int r = 0; r < 4; ++r) rl[r] = 1.0f / __shfl(rsum, quad * 4 + r);
        #pragma unroll
        for (int t = 0; t < 4; ++t)
            #pragma unroll
            for (int r = 0; r < 4; ++r) {
                size_t row = (size_t)b * SS + qb + g * 16 + quad * 4 + r;
                ctx[row * 1024 + h * 64 + t * 16 + lm] = __float2bfloat16(o[g][t][r] * rl[r]);
            }
    }
}

// ---------------------------------------------------------------- launch (4 dispatches)
extern "C" void kernel_launch(void* const* d_in, const int* in_sizes, int n_in,
                              void* d_out, int out_size, void* d_ws, size_t ws_size,
                              hipStream_t stream) {
    const float* x  = (const float*)d_in[0];
    const float* Wq = (const float*)d_in[1];
    const float* Wk = (const float*)d_in[2];
    const float* Wv = (const float*)d_in[3];
    const float* Wo = (const float*)d_in[4];
    const float* bo = (const float*)d_in[5];

    char* ws = (char*)d_ws;
    bf16* xb  = (bf16*)ws;  ws += (size_t)8192 * 1024 * 2;   // 16 MB (reused as ctx)
    bf16* wt  = (bf16*)ws;  ws += (size_t)3072 * 1024 * 2;   //  6 MB
    bf16* wob = (bf16*)ws;  ws += (size_t)1024 * 1024 * 2;   //  2 MB
    bf16* qkv = (bf16*)ws;  ws += (size_t)8192 * 3072 * 2;   // 48 MB (V third dead/unwritten)
    bf16* vtb = (bf16*)ws;  ws += (size_t)BB * NH * HDIM * SS * 2;  // 16 MB
    bf16* ctx = xb;  // xb dead after gemm_qkv -> alias

    prep_all_kernel<<<5376, 256, 0, stream>>>(x, Wq, Wk, Wv, Wo, xb, wt, wob);
    gemm_bt_kernel<0><<<dim3(64, 24), 256, 0, stream>>>(xb, wt, (void*)qkv, nullptr, 1024, 3072, vtb);
    flash_attn_kernel<<<1024, 256, 0, stream>>>(qkv, vtb, ctx);
    gemm_bt_kernel<1><<<dim3(64, 8), 256, 0, stream>>>(ctx, wob, d_out, bo, 1024, 1024, nullptr);
}

// Round 7
// 249.842 us; speedup vs baseline: 1.2962x; 1.0087x over previous
//
#include <hip/hip_runtime.h>
#include <hip/hip_bf16.h>

// Problem constants
#define BB   4
#define SS   2048
#define DIN  1024
#define DOUT 1024
#define NH   16
#define HDIM 64

typedef __hip_bfloat16 bf16;
typedef __attribute__((ext_vector_type(8))) short short8;   // bf16 MFMA A/B frag (4 VGPR)
typedef __attribute__((ext_vector_type(4))) float floatx4;  // MFMA C/D frag

#define AS1(p) ((const __attribute__((address_space(1))) void*)(p))
#define AS3(p) ((__attribute__((address_space(3))) void*)(p))

// ---------------------------------------------------------------- fused prep:
// bid [0,4096)      : cast x (f32 -> bf16), 8 elems/thread
// bid [4096,4864)   : build Wqkv^T tile (64x64 transpose + cast)
// bid [4864,5376)   : cast Wo (f32 -> bf16)
__global__ void prep_all_kernel(const float* __restrict__ x,
                                const float* __restrict__ Wq, const float* __restrict__ Wk,
                                const float* __restrict__ Wv, const float* __restrict__ Wo,
                                bf16* __restrict__ xb, bf16* __restrict__ wt,
                                bf16* __restrict__ wob) {
    __shared__ float tile[64][65];
    const int bid = blockIdx.x;
    const int tid = threadIdx.x;
    if (bid < 4096 || bid >= 4864) {
        const float* src = (bid < 4096) ? x : Wo;
        bf16* dst        = (bid < 4096) ? xb : wob;
        const int  rb    = (bid < 4096) ? bid : (bid - 4864);
        size_t i = ((size_t)rb * 256 + tid) * 8;
        float4 a = *(const float4*)(src + i);
        float4 b = *(const float4*)(src + i + 4);
        bf16 o[8] __attribute__((aligned(16)));
        o[0] = __float2bfloat16(a.x); o[1] = __float2bfloat16(a.y);
        o[2] = __float2bfloat16(a.z); o[3] = __float2bfloat16(a.w);
        o[4] = __float2bfloat16(b.x); o[5] = __float2bfloat16(b.y);
        o[6] = __float2bfloat16(b.z); o[7] = __float2bfloat16(b.w);
        *(short8*)(dst + i) = *(short8*)o;
        return;
    }
    // ---- prep Wqkv^T: rows = output col n, cols = k ----
    const int pb = bid - 4096;
    const int kt = pb & 15;             // 16 k-tiles
    const int nt = pb >> 4;             // 48 n-tiles
    const int k0 = kt * 64, n0 = nt * 64;
    const float* W = (n0 < 1024) ? Wq : (n0 < 2048 ? Wk : Wv);
    const int col0 = n0 & 1023;
    {
        const int kl = tid >> 2, nc = (tid & 3) * 16;
        const float* src = W + (size_t)(k0 + kl) * 1024 + col0 + nc;
        #pragma unroll
        for (int i = 0; i < 16; i += 4) {
            float4 v = *(const float4*)(src + i);
            tile[kl][nc + i + 0] = v.x; tile[kl][nc + i + 1] = v.y;
            tile[kl][nc + i + 2] = v.z; tile[kl][nc + i + 3] = v.w;
        }
    }
    __syncthreads();
    {
        const int nl = tid >> 2, kc = (tid & 3) * 16;
        bf16 o[16] __attribute__((aligned(16)));
        #pragma unroll
        for (int i = 0; i < 16; ++i) o[i] = __float2bfloat16(tile[kc + i][nl]);
        bf16* dst = wt + (size_t)(n0 + nl) * 1024 + k0 + kc;
        *(short8*)dst       = *(short8*)&o[0];
        *(short8*)(dst + 8) = *(short8*)&o[8];
    }
}

// ---------------------------------------------------------------- GEMM: C = A @ Bt^T
// R7: single-barrier double-buffered K-loop — the SAME loop structure as the flash kernel
// (proven correct/fast all session): each iteration {barrier; stage tile t+1 -> buf^1;
// read frags from buf[cur]; MFMA}. The compiler's vmcnt(0)+lgkmcnt(0) before s_barrier
// guarantees at the barrier: (1) tile t's DMA (issued last iter) landed, (2) every wave's
// ds_reads of buf^1 drained -> overwriting it is safe. One barrier drain per K-step, and
// the DMA flies under the whole tile-t compute (R6 had a second barrier right after the
// DMA issue -> full latency exposed every step).
// Retained from R6 (proven): BK=64, XOR chunk swizzle (pre-swizzled global source chunk
// (lane&7)^(lane>>3), ds_read chunk c^(row&7)) -> 0 bank conflicts; V-part of qkv written
// transposed straight to vt (EPI==0, rowB0>=2048). k-order identical -> same numerics.
// LDS 64 KB -> 2 blocks/CU; ILP (stage under compute) replaces the lost TLP.
template<int EPI>
__global__ __launch_bounds__(256) void gemm_bt_kernel(
    const bf16* __restrict__ A, const bf16* __restrict__ Bt,
    void* __restrict__ C, const float* __restrict__ bias, int K, int ldc,
    bf16* __restrict__ vt) {
    __shared__ __align__(16) bf16 As[2][128][64];
    __shared__ __align__(16) bf16 Bs[2][128][64];
    const int tid  = threadIdx.x;
    const int wave = tid >> 6, lane = tid & 63;
    const int lm   = lane & 15, quad = lane >> 4;
    const int wm   = (wave >> 1) * 64, wn = (wave & 1) * 64;
    const size_t rowA0 = (size_t)blockIdx.x * 128;
    const size_t rowB0 = (size_t)blockIdx.y * 128;

    const int srow8  = lane >> 3;            // row within 8-group == row&7
    const int schunk = (lane & 7) ^ srow8;   // pre-swizzled source chunk
    const int sw     = lm & 7;               // read-side row&7

    floatx4 acc[4][4] = {};

    // prologue: stage tile 0 -> buf 0 (first loop barrier waits for it)
    #pragma unroll
    for (int j = 0; j < 4; ++j) {
        const int rbase = (wave * 4 + j) * 8;
        const bf16* gA = A  + (rowA0 + rbase + srow8) * (size_t)K + schunk * 8;
        __builtin_amdgcn_global_load_lds(AS1(gA), AS3(&As[0][rbase][0]), 16, 0, 0);
        const bf16* gB = Bt + (rowB0 + rbase + srow8) * (size_t)K + schunk * 8;
        __builtin_amdgcn_global_load_lds(AS1(gB), AS3(&Bs[0][rbase][0]), 16, 0, 0);
    }

    const int nk = K >> 6;
    #pragma unroll 1
    for (int t = 0; t < nk; ++t) {
        const int cur = t & 1;
        __syncthreads();   // tile t landed (vmcnt drain); buf^1 readers done (lgkm drain)
        if (t + 1 < nk) {
            #pragma unroll
            for (int j = 0; j < 4; ++j) {
                const int rbase = (wave * 4 + j) * 8;
                const bf16* gA = A  + (rowA0 + rbase + srow8) * (size_t)K + (t + 1) * 64 + schunk * 8;
                __builtin_amdgcn_global_load_lds(AS1(gA), AS3(&As[cur ^ 1][rbase][0]), 16, 0, 0);
                const bf16* gB = Bt + (rowB0 + rbase + srow8) * (size_t)K + (t + 1) * 64 + schunk * 8;
                __builtin_amdgcn_global_load_lds(AS1(gB), AS3(&Bs[cur ^ 1][rbase][0]), 16, 0, 0);
            }
        }
        short8 a[4][2], b[4][2];
        #pragma unroll
        for (int i = 0; i < 4; ++i) {
            const int r = wm + i * 16 + lm;
            a[i][0] = *(const short8*)&As[cur][r][((quad    ) ^ sw) * 8];
            a[i][1] = *(const short8*)&As[cur][r][((quad + 4) ^ sw) * 8];
        }
        #pragma unroll
        for (int j = 0; j < 4; ++j) {
            const int r = wn + j * 16 + lm;
            b[j][0] = *(const short8*)&Bs[cur][r][((quad    ) ^ sw) * 8];
            b[j][1] = *(const short8*)&Bs[cur][r][((quad + 4) ^ sw) * 8];
        }
        __builtin_amdgcn_s_setprio(1);
        #pragma unroll
        for (int i = 0; i < 4; ++i)
            #pragma unroll
            for (int j = 0; j < 4; ++j) {
                acc[i][j] = __builtin_amdgcn_mfma_f32_16x16x32_bf16(a[i][0], b[j][0], acc[i][j], 0, 0, 0);
                acc[i][j] = __builtin_amdgcn_mfma_f32_16x16x32_bf16(a[i][1], b[j][1], acc[i][j], 0, 0, 0);
            }
        __builtin_amdgcn_s_setprio(0);
    }

    if (EPI == 0 && rowB0 >= 2048) {
        // V-part: write transposed into vt[((b*16+h)*64+hd)*SS + s]; skip dead qkv store.
        #pragma unroll
        for (int i = 0; i < 4; ++i) {
            size_t row = rowA0 + wm + i * 16 + quad * 4;   // = b*2048 + s, 4-aligned
            const size_t b = row >> 11;
            const int    s = (int)(row & 2047);
            #pragma unroll
            for (int j = 0; j < 4; ++j) {
                const int col = (int)(rowB0 - 2048) + wn + j * 16 + lm;   // h*64 + hd
                bf16 o[4] __attribute__((aligned(8)));
                #pragma unroll
                for (int r = 0; r < 4; ++r) o[r] = __float2bfloat16(acc[i][j][r]);
                *(uint64_t*)(vt + ((b * 16 + (col >> 6)) * 64 + (col & 63)) * (size_t)SS + s)
                    = *(uint64_t*)o;
            }
        }
        return;
    }

    #pragma unroll
    for (int i = 0; i < 4; ++i) {
        size_t row = rowA0 + wm + i * 16 + quad * 4;
        #pragma unroll
        for (int j = 0; j < 4; ++j) {
            size_t col = rowB0 + wn + j * 16 + lm;
            float bv = (EPI == 1) ? bias[col] : 0.0f;
            #pragma unroll
            for (int r = 0; r < 4; ++r) {
                if (EPI == 0)
                    ((bf16*)C)[(row + r) * ldc + col] = __float2bfloat16(acc[i][j][r]);
                else
                    ((float*)C)[(row + r) * ldc + col] = acc[i][j][r] + bv;
            }
        }
    }
}

// ---------------------------------------------------------------- causal flash attention v8
// v7 (grid 1024, 3 blocks/CU, heavy-first, single-barrier dbuf) + R7:
//  - wave-uniform SKIP of fully-masked tiles (kt*64 > qb+31): waves 0,1 of each block waste
//    their entire last tile today; skipped contributions are exact zeros (exp2(-1.8e29)=0)
//    -> bit-identical output. Staging + barriers still executed by all waves.
//  - T5 setprio(1) around the MFMA clusters only (m191: +4-7% attn; cross-block wave
//    diversity at 3 blocks/CU is the regime where it pays).
#define PSTR 68
__global__ __launch_bounds__(256, 3) void flash_attn_kernel(
    const bf16* __restrict__ qkv, const bf16* __restrict__ vt, bf16* __restrict__ ctx) {
    __shared__ __align__(16) bf16 Ks[2][64 * 64];       // double-buffered K tile
    __shared__ __align__(16) bf16 Vs[2][64 * 64];       // double-buffered V tile
    __shared__ __align__(16) bf16 Pl[4][32 * PSTR + 8]; // per-wave P (C->A layout)
    const int tid  = threadIdx.x;
    const int wave = tid >> 6, lane = tid & 63;
    const int lm   = lane & 15, quad = lane >> 4;

    const int id  = blockIdx.x;          // 0..1023
    const int jl  = (id >> 3) & 7;
    const int bh  = (id & 7) * 8 + jl;
    const int p   = 15 - (id >> 6);      // q-tile index, heavy first
    const int b = bh >> 4, h = bh & 15;

    const int lane8r = lane >> 3;        // == row & 7
    const int schunk = (lane & 7) ^ lane8r;

    const bf16* kg = qkv + (size_t)b * SS * 3072 + 1024 + h * 64 + schunk * 8;
    const bf16* vg = vt + (size_t)(b * NH + h) * 64 * SS + schunk * 8;

    bf16* Pw = &Pl[wave][0];

    const int qb = p * 128 + wave * 32;      // wave's first q row
    const int nkt = 2 * p + 2;

    short8 bq[2][2];
    #pragma unroll
    for (int g = 0; g < 2; ++g) {
        const bf16* qp = qkv + ((size_t)(b * SS + qb + g * 16 + lm)) * 3072 + h * 64 + quad * 8;
        bq[g][0] = *(const short8*)qp;
        bq[g][1] = *(const short8*)(qp + 32);
    }

    floatx4 o[2][4] = {};
    float lsum[2] = {0.f, 0.f};

    #pragma unroll
    for (int c = 0; c < 2; ++c) {
        const int row = c * 32 + wave * 8 + lane8r;
        __builtin_amdgcn_global_load_lds(AS1(kg + (size_t)row * 3072), AS3(&Ks[0][(c * 256 + wave * 64) * 8]), 16, 0, 0);
        __builtin_amdgcn_global_load_lds(AS1(vg + (size_t)row * SS), AS3(&Vs[0][(c * 256 + wave * 64) * 8]), 16, 0, 0);
    }

    #pragma unroll 1
    for (int kt = 0; kt < nkt; ++kt) {
        const int cur = kt & 1;
        __syncthreads();   // tile kt arrived (vmcnt drain); buf^1 readers done
        if (kt + 1 < nkt) {
            #pragma unroll
            for (int c = 0; c < 2; ++c) {
                const int row = c * 32 + wave * 8 + lane8r;
                __builtin_amdgcn_global_load_lds(AS1(kg + (size_t)((kt + 1) * 64 + row) * 3072),
                                                 AS3(&Ks[cur ^ 1][(c * 256 + wave * 64) * 8]), 16, 0, 0);
                __builtin_amdgcn_global_load_lds(AS1(vg + (size_t)row * SS + (kt + 1) * 64),
                                                 AS3(&Vs[cur ^ 1][(c * 256 + wave * 64) * 8]), 16, 0, 0);
            }
        }

        // wave-uniform skip: this tile's keys are all > this wave's max q row -> exact 0s
        if (kt * 64 > qb + 31) continue;

        const int sw = lm & 7;
        const bf16* Ksb = &Ks[cur][0];
        const bf16* Vsb = &Vs[cur][0];
        short8 ka[4][2], va[4][2];
        #pragma unroll
        for (int nt = 0; nt < 4; ++nt) {
            const int r0 = (nt * 16 + lm) * 64;
            ka[nt][0] = *(const short8*)(Ksb + r0 + ((quad ^ sw) * 8));
            ka[nt][1] = *(const short8*)(Ksb + r0 + (((4 + quad) ^ sw) * 8));
            va[nt][0] = *(const short8*)(Vsb + r0 + ((quad ^ sw) * 8));
            va[nt][1] = *(const short8*)(Vsb + r0 + (((4 + quad) ^ sw) * 8));
        }

        #pragma unroll
        for (int g = 0; g < 2; ++g) {
            floatx4 sc[4];
            __builtin_amdgcn_s_setprio(1);
            #pragma unroll
            for (int nt = 0; nt < 4; ++nt) {
                floatx4 z = {};
                z = __builtin_amdgcn_mfma_f32_16x16x32_bf16(ka[nt][0], bq[g][0], z, 0, 0, 0);
                z = __builtin_amdgcn_mfma_f32_16x16x32_bf16(ka[nt][1], bq[g][1], z, 0, 0, 0);
                sc[nt] = z;
            }
            __builtin_amdgcn_s_setprio(0);
            if (kt * 64 + 63 > qb + g * 16) {
                const int qrow = qb + g * 16 + lm;
                #pragma unroll
                for (int nt = 0; nt < 4; ++nt)
                    #pragma unroll
                    for (int r = 0; r < 4; ++r)
                        if (kt * 64 + nt * 16 + quad * 4 + r > qrow) sc[nt][r] = -1e30f;
            }
            #pragma unroll
            for (int nt = 0; nt < 4; ++nt) {
                bf16 pk[4] __attribute__((aligned(8)));
                #pragma unroll
                for (int r = 0; r < 4; ++r) {
                    float pv = __builtin_amdgcn_exp2f(sc[nt][r] * 0.18033688f);
                    lsum[g] += pv;
                    pk[r] = __float2bfloat16(pv);
                }
                *(uint64_t*)&Pw[(g * 16 + lm) * PSTR + nt * 16 + quad * 4] = *(uint64_t*)pk;
            }
        }
        #pragma unroll
        for (int g = 0; g < 2; ++g) {
            const short8 ap0 = *(const short8*)&Pw[(g * 16 + lm) * PSTR + quad * 8];
            const short8 ap1 = *(const short8*)&Pw[(g * 16 + lm) * PSTR + 32 + quad * 8];
            __builtin_amdgcn_s_setprio(1);
            #pragma unroll
            for (int t = 0; t < 4; ++t) {
                o[g][t] = __builtin_amdgcn_mfma_f32_16x16x32_bf16(ap0, va[t][0], o[g][t], 0, 0, 0);
                o[g][t] = __builtin_amdgcn_mfma_f32_16x16x32_bf16(ap1, va[t][1], o[g][t], 0, 0, 0);
            }
            __builtin_amdgcn_s_setprio(0);
        }
    }

    #pragma unroll
    for (int g = 0; g < 2; ++g) {
        float rsum = lsum[g];
        rsum += __shfl_xor(rsum, 16);
        rsum += __shfl_xor(rsum, 32);
        float rl[4];
        #pragma unroll
        for (int r = 0; r < 4; ++r) rl[r] = 1.0f / __shfl(rsum, quad * 4 + r);
        #pragma unroll
        for (int t = 0; t < 4; ++t)
            #pragma unroll
            for (int r = 0; r < 4; ++r) {
                size_t row = (size_t)b * SS + qb + g * 16 + quad * 4 + r;
                ctx[row * 1024 + h * 64 + t * 16 + lm] = __float2bfloat16(o[g][t][r] * rl[r]);
            }
    }
}

// ---------------------------------------------------------------- launch (4 dispatches)
extern "C" void kernel_launch(void* const* d_in, const int* in_sizes, int n_in,
                              void* d_out, int out_size, void* d_ws, size_t ws_size,
                              hipStream_t stream) {
    const float* x  = (const float*)d_in[0];
    const float* Wq = (const float*)d_in[1];
    const float* Wk = (const float*)d_in[2];
    const float* Wv = (const float*)d_in[3];
    const float* Wo = (const float*)d_in[4];
    const float* bo = (const float*)d_in[5];

    char* ws = (char*)d_ws;
    bf16* xb  = (bf16*)ws;  ws += (size_t)8192 * 1024 * 2;   // 16 MB (reused as ctx)
    bf16* wt  = (bf16*)ws;  ws += (size_t)3072 * 1024 * 2;   //  6 MB
    bf16* wob = (bf16*)ws;  ws += (size_t)1024 * 1024 * 2;   //  2 MB
    bf16* qkv = (bf16*)ws;  ws += (size_t)8192 * 3072 * 2;   // 48 MB (V third dead/unwritten)
    bf16* vtb = (bf16*)ws;  ws += (size_t)BB * NH * HDIM * SS * 2;  // 16 MB
    bf16* ctx = xb;  // xb dead after gemm_qkv -> alias

    prep_all_kernel<<<5376, 256, 0, stream>>>(x, Wq, Wk, Wv, Wo, xb, wt, wob);
    gemm_bt_kernel<0><<<dim3(64, 24), 256, 0, stream>>>(xb, wt, (void*)qkv, nullptr, 1024, 3072, vtb);
    flash_attn_kernel<<<1024, 256, 0, stream>>>(qkv, vtb, ctx);
    gemm_bt_kernel<1><<<dim3(64, 8), 256, 0, stream>>>(ctx, wob, d_out, bo, 1024, 1024, nullptr);
}